// Round 1
// baseline (1422.682 us; speedup 1.0000x reference)
//
#include <hip/hip_runtime.h>
#include <hip/hip_bf16.h>

// Problem shapes (fixed by setup_inputs):
//   x:(16,32,128) mask:(16,128) w1:(256,66) b1:(256) w2:(128,256) b2:(128) pool_w:(128,21)
//   L=128, L2=16384, dim=256, out_c=128, n_pieces=20. Output: (16,128) f32.

#define NB 16
#define CIN 33
#define DIM 256
#define LEN 128
#define OC 128
#define L2 16384

// ---------------- kernel A: ha/hb = w1a/w1b @ xm ----------------
__global__ __launch_bounds__(128) void kA(const float* __restrict__ x,
                                          const float* __restrict__ mask,
                                          const float* __restrict__ w1,
                                          float* __restrict__ ha,
                                          float* __restrict__ hb) {
    int d = blockIdx.x;          // 0..255
    int n = blockIdx.y;          // 0..15
    int l = threadIdx.x;         // 0..127
    const float* w1r = w1 + d * (2 * CIN);
    float a = 0.f, b = 0.f;
#pragma unroll
    for (int c = 0; c < CIN; ++c) {
        float xv = (c < 32) ? x[((size_t)n * 32 + c) * LEN + l] : mask[(size_t)n * LEN + l];
        a = fmaf(w1r[c], xv, a);
        b = fmaf(w1r[CIN + c], xv, b);
    }
    ha[((size_t)n * DIM + d) * LEN + l] = a;
    hb[((size_t)n * DIM + d) * LEN + l] = b;
}

// ---------------- kernel B: y[n,o,i,j] = sum_d w2[o,d]*relu(ha[d,i]+hb[d,j]+b1[d]) + b2[o] ----
// block: 256 threads -> tile 8 i x 32 j, all 128 o in chunks of 32.
// grid: (jt=4, it=16, nloc)
__global__ __launch_bounds__(256) void kB(const float* __restrict__ ha,
                                          const float* __restrict__ hb,
                                          const float* __restrict__ b1,
                                          const float* __restrict__ w2,
                                          const float* __restrict__ b2,
                                          float* __restrict__ y,
                                          int nbase) {
    __shared__ float ha_s[DIM * 8];
    __shared__ float hb_s[DIM * 32];
    int jt = blockIdx.x, it = blockIdx.y, zloc = blockIdx.z;
    int n = nbase + zloc;
    int tid = threadIdx.x;
    int tj = tid & 31, ti = tid >> 5;
    int i0 = it * 8, j0 = jt * 32;
    const float* haN = ha + (size_t)n * DIM * LEN;
    const float* hbN = hb + (size_t)n * DIM * LEN;
    for (int idx = tid; idx < DIM * 8; idx += 256) {
        int d = idx >> 3, ii = idx & 7;
        ha_s[idx] = haN[d * LEN + i0 + ii];
    }
    for (int idx = tid; idx < DIM * 32; idx += 256) {
        int d = idx >> 5, jj = idx & 31;
        hb_s[idx] = hbN[d * LEN + j0 + jj];
    }
    __syncthreads();
    int i = i0 + ti, j = j0 + tj;
    float* yrow = y + (size_t)zloc * OC * L2 + (size_t)i * LEN + j;
    for (int oc = 0; oc < OC; oc += 32) {
        float acc[32];
#pragma unroll
        for (int oo = 0; oo < 32; ++oo) acc[oo] = 0.f;
        for (int d = 0; d < DIM; ++d) {
            float h = ha_s[d * 8 + ti] + hb_s[d * 32 + tj] + b1[d];
            h = fmaxf(h, 0.f);
            const float* w2p = w2 + (size_t)oc * DIM + d;   // uniform address -> s_load expected
#pragma unroll
            for (int oo = 0; oo < 32; ++oo)
                acc[oo] = fmaf(w2p[(size_t)oo * DIM], h, acc[oo]);
        }
#pragma unroll
        for (int oo = 0; oo < 32; ++oo)
            yrow[(size_t)(oc + oo) * L2] = acc[oo] + b2[oc + oo];
    }
}

// ---------------- kernel C: per-(n,o) row: bitonic sort desc + piecewise-linear weighted sum ----
__global__ __launch_bounds__(1024) void kC(const float* __restrict__ y,
                                           const float* __restrict__ pw,
                                           float* __restrict__ out,
                                           int nbase) {
    extern __shared__ float s[];   // 16384 floats = 64 KB
    const int N = L2;
    int row = blockIdx.x;          // zloc*128 + o
    int o = row & (OC - 1);
    int n = nbase + (row >> 7);
    int tid = threadIdx.x;
    const float* yr = y + (size_t)row * N;
    for (int r = tid; r < N; r += 1024) s[r] = yr[r];
    __syncthreads();
    // bitonic sort ascending in LDS
    for (int k = 2; k <= N; k <<= 1) {
        for (int jj = k >> 1; jj > 0; jj >>= 1) {
            for (int t = tid; t < N / 2; t += 1024) {
                int i = ((t & ~(jj - 1)) << 1) | (t & (jj - 1));
                int ix = i | jj;
                float a = s[i], b = s[ix];
                bool up = ((i & k) == 0);
                if ((a > b) == up) { s[i] = b; s[ix] = a; }
            }
            __syncthreads();
        }
    }
    // weighted sum: descending rank r -> s[N-1-r]
    float acc = 0.f;
    const float* pwo = pw + o * 21;
    for (int r = tid; r < N; r += 1024) {
        float v = s[N - 1 - r];
        float pos = fminf((float)r / 16383.0f, 1.0f);
        float idxf = 20.0f * pos;
        int idx = (int)idxf;
        float frac = idxf - (float)idx;
        int i1 = min(idx + 1, 20);
        float wv = (1.0f - frac) * pwo[idx] + frac * pwo[i1];
        acc = fmaf(v, wv, acc);
    }
    __syncthreads();
    s[tid] = acc;
    __syncthreads();
    for (int off = 512; off > 0; off >>= 1) {
        if (tid < off) s[tid] += s[tid + off];
        __syncthreads();
    }
    if (tid == 0) out[(size_t)n * OC + o] = s[0] * (1.0f / 16384.0f);
}

extern "C" void kernel_launch(void* const* d_in, const int* in_sizes, int n_in,
                              void* d_out, int out_size, void* d_ws, size_t ws_size,
                              hipStream_t stream) {
    const float* x    = (const float*)d_in[0];
    const float* mask = (const float*)d_in[1];
    const float* w1   = (const float*)d_in[2];
    const float* b1   = (const float*)d_in[3];
    const float* w2   = (const float*)d_in[4];
    const float* b2   = (const float*)d_in[5];
    const float* pw   = (const float*)d_in[6];
    float* out = (float*)d_out;

    float* ha = (float*)d_ws;
    float* hb = ha + (size_t)NB * DIM * LEN;
    float* y  = hb + (size_t)NB * DIM * LEN;
    size_t used = (size_t)2 * NB * DIM * LEN * sizeof(float);
    size_t perN = (size_t)OC * L2 * sizeof(float);   // 8 MB per n
    int nchunk = 1;
    if (ws_size > used + perN) {
        size_t c = (ws_size - used) / perN;
        nchunk = (int)(c > NB ? NB : c);
    }

    hipLaunchKernelGGL(kA, dim3(DIM, NB), dim3(128), 0, stream, x, mask, w1, ha, hb);
    for (int base = 0; base < NB; base += nchunk) {
        int nc = nchunk < (NB - base) ? nchunk : (NB - base);
        hipLaunchKernelGGL(kB, dim3(4, 16, nc), dim3(256), 0, stream, ha, hb, b1, w2, b2, y, base);
        hipLaunchKernelGGL(kC, dim3(OC * nc), dim3(1024), 65536, stream, y, pw, out, base);
    }
}

// Round 2
// 713.662 us; speedup vs baseline: 1.9935x; 1.9935x over previous
//
#include <hip/hip_runtime.h>
#include <hip/hip_bf16.h>

// Shapes: x:(16,32,128) mask:(16,128) w1:(256,66) b1:(256) w2:(128,256) b2:(128) pool_w:(128,21)
// L=128, L2=16384, dim=256, out_c=128. Output (16,128) f32.

#define NB 16
#define CIN 33
#define DIM 256
#define LEN 128
#define OC 128
#define L2 16384

// ---------------- kernel A: ha/hb = w1a/w1b @ xm, with b1 folded in (half each) ----------------
__global__ __launch_bounds__(128) void kA(const float* __restrict__ x,
                                          const float* __restrict__ mask,
                                          const float* __restrict__ w1,
                                          const float* __restrict__ b1,
                                          float* __restrict__ ha,
                                          float* __restrict__ hb) {
    int d = blockIdx.x;          // 0..255
    int n = blockIdx.y;          // 0..15
    int l = threadIdx.x;         // 0..127
    const float* w1r = w1 + d * (2 * CIN);
    float a = 0.f, b = 0.f;
#pragma unroll
    for (int c = 0; c < CIN; ++c) {
        float xv = (c < 32) ? x[((size_t)n * 32 + c) * LEN + l] : mask[(size_t)n * LEN + l];
        a = fmaf(w1r[c], xv, a);
        b = fmaf(w1r[CIN + c], xv, b);
    }
    float hb1 = 0.5f * b1[d];
    ha[((size_t)n * DIM + d) * LEN + l] = a + hb1;
    hb[((size_t)n * DIM + d) * LEN + l] = b + hb1;
}

// ---------------- kernel B: y[n,o,i,j] = sum_d w2[o,d]*relu(ha'[d,i]+hb'[d,j]) + b2[o] ----
// block 256 thr = 16tx x 16ty. Tile: o=0..127 (ty*8), i = 2 rows (blockIdx.x*2), j full 128 (tx*8).
// d staged in chunks of 32. Thread accs: 8o x 2i x 8j = 128.
#define DCH 32
#define PAD 132
__global__ __launch_bounds__(256) void kB(const float* __restrict__ ha,
                                          const float* __restrict__ hb,
                                          const float* __restrict__ w2,
                                          const float* __restrict__ b2,
                                          float* __restrict__ y,
                                          int nbase) {
    __shared__ float w2_s[DCH * PAD];
    __shared__ float hb_s[DCH * PAD];
    __shared__ float ha_s[DCH * 2];
    int iPair = blockIdx.x;      // 0..63
    int zloc = blockIdx.y;
    int n = nbase + zloc;
    int tid = threadIdx.x;
    int tx = tid & 15, ty = tid >> 4;
    int i0 = iPair * 2;
    const float* haN = ha + (size_t)n * DIM * LEN;
    const float* hbN = hb + (size_t)n * DIM * LEN;

    float acc[8][2][8];
#pragma unroll
    for (int a1 = 0; a1 < 8; ++a1)
#pragma unroll
        for (int a2 = 0; a2 < 2; ++a2)
#pragma unroll
            for (int a3 = 0; a3 < 8; ++a3) acc[a1][a2][a3] = 0.f;

    for (int d0 = 0; d0 < DIM; d0 += DCH) {
        __syncthreads();   // protect previous chunk's reads
        // stage w2 transposed: w2_s[dd][o] = w2[o][d0+dd]
        {
            int o = tid & 127, dh = tid >> 7;       // dh 0/1 -> 16 d each
            const float* g = w2 + (size_t)o * DIM + d0 + dh * 16;
#pragma unroll
            for (int q = 0; q < 4; ++q) {
                float4 v4 = *(const float4*)&g[q * 4];
                w2_s[(dh * 16 + q * 4 + 0) * PAD + o] = v4.x;
                w2_s[(dh * 16 + q * 4 + 1) * PAD + o] = v4.y;
                w2_s[(dh * 16 + q * 4 + 2) * PAD + o] = v4.z;
                w2_s[(dh * 16 + q * 4 + 3) * PAD + o] = v4.w;
            }
        }
        // stage hb rows: hb_s[dd][j]
        {
            int dd = tid >> 3, c0 = (tid & 7) * 16;
            const float* g = hbN + (size_t)(d0 + dd) * LEN + c0;
#pragma unroll
            for (int q = 0; q < 4; ++q)
                *(float4*)&hb_s[dd * PAD + c0 + q * 4] = *(const float4*)&g[q * 4];
        }
        // stage ha pairs
        if (tid < DCH * 2) {
            int dd = tid >> 1, ii = tid & 1;
            ha_s[dd * 2 + ii] = haN[(size_t)(d0 + dd) * LEN + i0 + ii];
        }
        __syncthreads();

#pragma unroll 4
        for (int dd = 0; dd < DCH; ++dd) {
            float4 wa = *(const float4*)&w2_s[dd * PAD + ty * 8];
            float4 wb = *(const float4*)&w2_s[dd * PAD + ty * 8 + 4];
            float4 ba = *(const float4*)&hb_s[dd * PAD + tx * 8];
            float4 bb = *(const float4*)&hb_s[dd * PAD + tx * 8 + 4];
            float a0 = ha_s[dd * 2 + 0], a1 = ha_s[dd * 2 + 1];
            float hbv[8] = {ba.x, ba.y, ba.z, ba.w, bb.x, bb.y, bb.z, bb.w};
            float w2v[8] = {wa.x, wa.y, wa.z, wa.w, wb.x, wb.y, wb.z, wb.w};
            float h0[8], h1[8];
#pragma unroll
            for (int c = 0; c < 8; ++c) {
                h0[c] = fmaxf(a0 + hbv[c], 0.f);
                h1[c] = fmaxf(a1 + hbv[c], 0.f);
            }
#pragma unroll
            for (int oo = 0; oo < 8; ++oo) {
                float w = w2v[oo];
#pragma unroll
                for (int c = 0; c < 8; ++c) {
                    acc[oo][0][c] = fmaf(w, h0[c], acc[oo][0][c]);
                    acc[oo][1][c] = fmaf(w, h1[c], acc[oo][1][c]);
                }
            }
        }
    }

    // epilogue: + b2, store
#pragma unroll
    for (int oo = 0; oo < 8; ++oo) {
        int o = ty * 8 + oo;
        float bv = b2[o];
#pragma unroll
        for (int ii = 0; ii < 2; ++ii) {
            float* yr = y + ((size_t)zloc * OC + o) * L2 + (size_t)(i0 + ii) * LEN + tx * 8;
            float4 s0 = make_float4(acc[oo][ii][0] + bv, acc[oo][ii][1] + bv,
                                    acc[oo][ii][2] + bv, acc[oo][ii][3] + bv);
            float4 s1 = make_float4(acc[oo][ii][4] + bv, acc[oo][ii][5] + bv,
                                    acc[oo][ii][6] + bv, acc[oo][ii][7] + bv);
            *(float4*)&yr[0] = s0;
            *(float4*)&yr[4] = s1;
        }
    }
}

// ---------------- kernel C: registerized bitonic sort (16 elem/thread) + weighted sum ----------
__device__ __forceinline__ void ce(float& a, float& b, bool up) {
    float lo = fminf(a, b), hi = fmaxf(a, b);
    a = up ? lo : hi;
    b = up ? hi : lo;
}

// LDS word index for thread t, element-group q (4 floats): bank-conflict-free XOR swizzle
__device__ __forceinline__ int widx(int t, int q) {
    return t * 16 + ((q ^ ((t >> 1) & 3)) << 2);
}

__global__ __launch_bounds__(1024) void kC(const float* __restrict__ y,
                                           const float* __restrict__ pw,
                                           float* __restrict__ out,
                                           int nbase) {
    extern __shared__ float s[];     // 16384 floats = 64 KB
    int row = blockIdx.x;            // zloc*128 + o
    int och = row & (OC - 1);
    int n = nbase + (row >> 7);
    int t = threadIdx.x;             // 0..1023
    const float* yr = y + (size_t)row * L2;

    float v[16];
#pragma unroll
    for (int q = 0; q < 4; ++q) {
        float4 v4 = *(const float4*)&yr[t * 16 + q * 4];
        v[q * 4 + 0] = v4.x; v[q * 4 + 1] = v4.y; v[q * 4 + 2] = v4.z; v[q * 4 + 3] = v4.w;
    }

    // ---- local phases k=2,4,8 (direction varies with e) ----
#pragma unroll
    for (int k = 2; k <= 8; k <<= 1) {
#pragma unroll
        for (int j = 8; j >= 1; j >>= 1) {
            if (j > (k >> 1)) continue;
#pragma unroll
            for (int e = 0; e < 16; ++e)
                if (!(e & j)) ce(v[e], v[e ^ j], ((e & k) == 0));
        }
    }
    // ---- k=16: direction uniform per thread ----
    {
        bool up16 = ((t & 1) == 0);
#pragma unroll
        for (int j = 8; j >= 1; j >>= 1)
#pragma unroll
            for (int e = 0; e < 16; ++e)
                if (!(e & j)) ce(v[e], v[e ^ j], up16);
    }
    // ---- main phases k=32..16384 ----
    for (int m = 5; m <= 14; ++m) {
        int k = 1 << m;
        bool up = ((t & (k >> 4)) == 0);
        for (int j = k >> 1; j >= 16; j >>= 1) {
            int delta = j >> 4;          // thread-xor distance
            bool lower = ((t & delta) == 0);
            bool keepmin = (lower == up);
            if (delta < 64) {            // same wave: shuffle exchange
#pragma unroll
                for (int e = 0; e < 16; ++e) {
                    float pv = __shfl_xor(v[e], delta, 64);
                    v[e] = keepmin ? fminf(v[e], pv) : fmaxf(v[e], pv);
                }
            } else {                     // cross-wave: LDS exchange (swizzled float4)
                int p = t ^ delta;
#pragma unroll
                for (int q = 0; q < 4; ++q) {
                    *(float4*)&s[widx(t, q)] =
                        make_float4(v[q * 4], v[q * 4 + 1], v[q * 4 + 2], v[q * 4 + 3]);
                }
                __syncthreads();
#pragma unroll
                for (int q = 0; q < 4; ++q) {
                    float4 pv = *(const float4*)&s[widx(p, q)];
                    float pe[4] = {pv.x, pv.y, pv.z, pv.w};
#pragma unroll
                    for (int c = 0; c < 4; ++c) {
                        int e = q * 4 + c;
                        v[e] = keepmin ? fminf(v[e], pe[c]) : fmaxf(v[e], pe[c]);
                    }
                }
                __syncthreads();
            }
        }
        // local tail j=8..1, uniform direction
#pragma unroll
        for (int j = 8; j >= 1; j >>= 1)
#pragma unroll
            for (int e = 0; e < 16; ++e)
                if (!(e & j)) ce(v[e], v[e ^ j], up);
    }

    // ---- weighted sum: ascending pos = t*16+e, descending rank r = 16383-pos ----
    float accum = 0.f;
    const float* pwo = pw + och * 21;
#pragma unroll
    for (int e = 0; e < 16; ++e) {
        int pos = t * 16 + e;
        int r = (L2 - 1) - pos;
        float posf = fminf((float)r / 16383.0f, 1.0f);
        float idxf = 20.0f * posf;
        int idx = (int)idxf;
        float frac = idxf - (float)idx;
        int i1 = min(idx + 1, 20);
        float wv = (1.0f - frac) * pwo[idx] + frac * pwo[i1];
        accum = fmaf(v[e], wv, accum);
    }
    // block reduce
#pragma unroll
    for (int d2 = 32; d2 >= 1; d2 >>= 1) accum += __shfl_xor(accum, d2, 64);
    if ((t & 63) == 0) s[t >> 6] = accum;
    __syncthreads();
    if (t == 0) {
        float tot = 0.f;
#pragma unroll
        for (int wv2 = 0; wv2 < 16; ++wv2) tot += s[wv2];
        out[(size_t)n * OC + och] = tot * (1.0f / (float)L2);
    }
}

extern "C" void kernel_launch(void* const* d_in, const int* in_sizes, int n_in,
                              void* d_out, int out_size, void* d_ws, size_t ws_size,
                              hipStream_t stream) {
    const float* x    = (const float*)d_in[0];
    const float* mask = (const float*)d_in[1];
    const float* w1   = (const float*)d_in[2];
    const float* b1   = (const float*)d_in[3];
    const float* w2   = (const float*)d_in[4];
    const float* b2   = (const float*)d_in[5];
    const float* pw   = (const float*)d_in[6];
    float* out = (float*)d_out;

    float* ha = (float*)d_ws;
    float* hb = ha + (size_t)NB * DIM * LEN;
    float* y  = hb + (size_t)NB * DIM * LEN;
    size_t used = (size_t)2 * NB * DIM * LEN * sizeof(float);
    size_t perN = (size_t)OC * L2 * sizeof(float);   // 8 MB per n
    int nchunk = 1;
    if (ws_size > used + perN) {
        size_t c = (ws_size - used) / perN;
        nchunk = (int)(c > NB ? NB : c);
    }

    hipLaunchKernelGGL(kA, dim3(DIM, NB), dim3(128), 0, stream, x, mask, w1, b1, ha, hb);
    for (int base = 0; base < NB; base += nchunk) {
        int nc = nchunk < (NB - base) ? nchunk : (NB - base);
        hipLaunchKernelGGL(kB, dim3(64, nc), dim3(256), 0, stream, ha, hb, w2, b2, y, base);
        hipLaunchKernelGGL(kC, dim3(OC * nc), dim3(1024), 65536, stream, y, pw, out, base);
    }
}

// Round 3
// 493.973 us; speedup vs baseline: 2.8801x; 1.4447x over previous
//
#include <hip/hip_runtime.h>
#include <hip/hip_bf16.h>

// Shapes: x:(16,32,128) mask:(16,128) w1:(256,66) b1:(256) w2:(128,256) b2:(128) pool_w:(128,21)
// L=128, L2=16384, dim=256, out_c=128. Output (16,128) f32.

#define NB 16
#define CIN 33
#define DIM 256
#define LEN 128
#define OC 128
#define L2 16384

// ---------------- kernel A: ha/hb = w1a/w1b @ xm, with b1 folded in (half each) ----------------
__global__ __launch_bounds__(128) void kA(const float* __restrict__ x,
                                          const float* __restrict__ mask,
                                          const float* __restrict__ w1,
                                          const float* __restrict__ b1,
                                          float* __restrict__ ha,
                                          float* __restrict__ hb) {
    int d = blockIdx.x;
    int n = blockIdx.y;
    int l = threadIdx.x;
    const float* w1r = w1 + d * (2 * CIN);
    float a = 0.f, b = 0.f;
#pragma unroll
    for (int c = 0; c < CIN; ++c) {
        float xv = (c < 32) ? x[((size_t)n * 32 + c) * LEN + l] : mask[(size_t)n * LEN + l];
        a = fmaf(w1r[c], xv, a);
        b = fmaf(w1r[CIN + c], xv, b);
    }
    float hb1 = 0.5f * b1[d];
    ha[((size_t)n * DIM + d) * LEN + l] = a + hb1;
    hb[((size_t)n * DIM + d) * LEN + l] = b + hb1;
}

// ---------------- kernel B: y[n,o,i,j] = sum_d w2[o,d]*relu(ha'[d,i]+hb'[d,j]) + b2[o] ----
#define DCH 32
#define PAD 132
__global__ __launch_bounds__(256) void kB(const float* __restrict__ ha,
                                          const float* __restrict__ hb,
                                          const float* __restrict__ w2,
                                          const float* __restrict__ b2,
                                          float* __restrict__ y,
                                          int nbase) {
    __shared__ float w2_s[DCH * PAD];
    __shared__ float hb_s[DCH * PAD];
    __shared__ float ha_s[DCH * 2];
    int iPair = blockIdx.x;
    int zloc = blockIdx.y;
    int n = nbase + zloc;
    int tid = threadIdx.x;
    int tx = tid & 15, ty = tid >> 4;
    int i0 = iPair * 2;
    const float* haN = ha + (size_t)n * DIM * LEN;
    const float* hbN = hb + (size_t)n * DIM * LEN;

    float acc[8][2][8];
#pragma unroll
    for (int a1 = 0; a1 < 8; ++a1)
#pragma unroll
        for (int a2 = 0; a2 < 2; ++a2)
#pragma unroll
            for (int a3 = 0; a3 < 8; ++a3) acc[a1][a2][a3] = 0.f;

    for (int d0 = 0; d0 < DIM; d0 += DCH) {
        __syncthreads();
        {
            int o = tid & 127, dh = tid >> 7;
            const float* g = w2 + (size_t)o * DIM + d0 + dh * 16;
#pragma unroll
            for (int q = 0; q < 4; ++q) {
                float4 v4 = *(const float4*)&g[q * 4];
                w2_s[(dh * 16 + q * 4 + 0) * PAD + o] = v4.x;
                w2_s[(dh * 16 + q * 4 + 1) * PAD + o] = v4.y;
                w2_s[(dh * 16 + q * 4 + 2) * PAD + o] = v4.z;
                w2_s[(dh * 16 + q * 4 + 3) * PAD + o] = v4.w;
            }
        }
        {
            int dd = tid >> 3, c0 = (tid & 7) * 16;
            const float* g = hbN + (size_t)(d0 + dd) * LEN + c0;
#pragma unroll
            for (int q = 0; q < 4; ++q)
                *(float4*)&hb_s[dd * PAD + c0 + q * 4] = *(const float4*)&g[q * 4];
        }
        if (tid < DCH * 2) {
            int dd = tid >> 1, ii = tid & 1;
            ha_s[dd * 2 + ii] = haN[(size_t)(d0 + dd) * LEN + i0 + ii];
        }
        __syncthreads();

#pragma unroll 4
        for (int dd = 0; dd < DCH; ++dd) {
            float4 wa = *(const float4*)&w2_s[dd * PAD + ty * 8];
            float4 wb = *(const float4*)&w2_s[dd * PAD + ty * 8 + 4];
            float4 ba = *(const float4*)&hb_s[dd * PAD + tx * 8];
            float4 bb = *(const float4*)&hb_s[dd * PAD + tx * 8 + 4];
            float a0 = ha_s[dd * 2 + 0], a1 = ha_s[dd * 2 + 1];
            float hbv[8] = {ba.x, ba.y, ba.z, ba.w, bb.x, bb.y, bb.z, bb.w};
            float w2v[8] = {wa.x, wa.y, wa.z, wa.w, wb.x, wb.y, wb.z, wb.w};
            float h0[8], h1[8];
#pragma unroll
            for (int c = 0; c < 8; ++c) {
                h0[c] = fmaxf(a0 + hbv[c], 0.f);
                h1[c] = fmaxf(a1 + hbv[c], 0.f);
            }
#pragma unroll
            for (int oo = 0; oo < 8; ++oo) {
                float w = w2v[oo];
#pragma unroll
                for (int c = 0; c < 8; ++c) {
                    acc[oo][0][c] = fmaf(w, h0[c], acc[oo][0][c]);
                    acc[oo][1][c] = fmaf(w, h1[c], acc[oo][1][c]);
                }
            }
        }
    }

#pragma unroll
    for (int oo = 0; oo < 8; ++oo) {
        int o = ty * 8 + oo;
        float bv = b2[o];
#pragma unroll
        for (int ii = 0; ii < 2; ++ii) {
            float* yr = y + ((size_t)zloc * OC + o) * L2 + (size_t)(i0 + ii) * LEN + tx * 8;
            float4 s0 = make_float4(acc[oo][ii][0] + bv, acc[oo][ii][1] + bv,
                                    acc[oo][ii][2] + bv, acc[oo][ii][3] + bv);
            float4 s1 = make_float4(acc[oo][ii][4] + bv, acc[oo][ii][5] + bv,
                                    acc[oo][ii][6] + bv, acc[oo][ii][7] + bv);
            *(float4*)&yr[0] = s0;
            *(float4*)&yr[4] = s1;
        }
    }
}

// ---------------- kernel C: registerized bitonic sort, DPP/swizzle exchanges, framed uint keys ---
__device__ __forceinline__ void ce(float& a, float& b, bool up) {
    float lo = fminf(a, b), hi = fmaxf(a, b);
    a = up ? lo : hi;
    b = up ? hi : lo;
}
__device__ __forceinline__ unsigned umn(unsigned a, unsigned b) { return a < b ? a : b; }
__device__ __forceinline__ unsigned umx(unsigned a, unsigned b) { return a > b ? a : b; }

// partner fetch for thread-xor DELTA (wave-internal)
template<int D>
__device__ __forceinline__ unsigned xg(unsigned x) {
    if constexpr (D == 1)
        return (unsigned)__builtin_amdgcn_mov_dpp((int)x, 0xB1, 0xF, 0xF, false);   // quad_perm xor1
    else if constexpr (D == 2)
        return (unsigned)__builtin_amdgcn_mov_dpp((int)x, 0x4E, 0xF, 0xF, false);   // quad_perm xor2
    else if constexpr (D == 4) {
        int y = __builtin_amdgcn_mov_dpp((int)x, 0x141, 0xF, 0xF, false);           // half_mirror xor7
        return (unsigned)__builtin_amdgcn_mov_dpp(y, 0x1B, 0xF, 0xF, false);        // quad xor3 -> xor4
    } else if constexpr (D == 8) {
        int y = __builtin_amdgcn_mov_dpp((int)x, 0x140, 0xF, 0xF, false);           // row_mirror xor15
        return (unsigned)__builtin_amdgcn_mov_dpp(y, 0x141, 0xF, 0xF, false);       // xor7 -> xor8
    } else if constexpr (D == 16)
        return (unsigned)__builtin_amdgcn_ds_swizzle((int)x, 0x401F);               // xor16
    else
        return (unsigned)__shfl_xor((int)x, D, 64);                                 // delta 32
}

template<int D>
__device__ __forceinline__ void slayer(unsigned* s, int t) {
    const bool up_sel = (t & D) != 0;   // upper lane keeps max (in ascending frame)
#pragma unroll
    for (int e = 0; e < 16; ++e) {
        unsigned pv = xg<D>(s[e]);
        unsigned mn = umn(s[e], pv), mx = umx(s[e], pv);
        s[e] = up_sel ? mx : mn;
    }
}

// local tail j=8..1 (ascending frame)
__device__ __forceinline__ void ltail(unsigned* s) {
#pragma unroll
    for (int j = 8; j >= 1; j >>= 1)
#pragma unroll
        for (int e = 0; e < 16; ++e)
            if (!(e & j)) {
                unsigned a = s[e], b = s[e ^ j];
                s[e] = umn(a, b);
                s[e ^ j] = umx(a, b);
            }
}

// LDS exchange for thread-xor DELTA >= 64; stride-12 layout, two 8-elem halves
template<int D>
__device__ __forceinline__ void llayer(unsigned* s, unsigned* lds, int t) {
    const bool up_sel = (t & D) != 0;
    const int p = t ^ D;
#pragma unroll
    for (int h = 0; h < 2; ++h) {
        uint4* wp = (uint4*)&lds[t * 12];
        wp[0] = make_uint4(s[h * 8 + 0], s[h * 8 + 1], s[h * 8 + 2], s[h * 8 + 3]);
        wp[1] = make_uint4(s[h * 8 + 4], s[h * 8 + 5], s[h * 8 + 6], s[h * 8 + 7]);
        __syncthreads();
        const uint4* rp = (const uint4*)&lds[p * 12];
        uint4 r0 = rp[0], r1 = rp[1];
        unsigned pe[8] = {r0.x, r0.y, r0.z, r0.w, r1.x, r1.y, r1.z, r1.w};
#pragma unroll
        for (int c = 0; c < 8; ++c) {
            unsigned a = s[h * 8 + c], b = pe[c];
            unsigned mn = umn(a, b), mx = umx(a, b);
            s[h * 8 + c] = up_sel ? mx : mn;
        }
        __syncthreads();
    }
}

#define REF(KS)                                         \
    {                                                   \
        unsigned nf = (t & (KS)) ? 0xFFFFFFFFu : 0u;    \
        unsigned dx = nf ^ F;                           \
        _Pragma("unroll") for (int e = 0; e < 16; ++e) s_[e] ^= dx; \
        F = nf;                                         \
    }

__global__ __launch_bounds__(1024, 8) void kC(const float* __restrict__ y,
                                              const float* __restrict__ pw,
                                              float* __restrict__ out,
                                              int nbase) {
    __shared__ unsigned sbuf[1024 * 12];   // 48 KB
    int row = blockIdx.x;
    int och = row & (OC - 1);
    int n = nbase + (row >> 7);
    int t = threadIdx.x;
    const float* yr = y + (size_t)row * L2;

    float v[16];
#pragma unroll
    for (int q = 0; q < 4; ++q) {
        float4 v4 = *(const float4*)&yr[t * 16 + q * 4];
        v[q * 4 + 0] = v4.x; v[q * 4 + 1] = v4.y; v[q * 4 + 2] = v4.z; v[q * 4 + 3] = v4.w;
    }

    // ---- float phases k=2,4,8 (direction varies by element bits) ----
#pragma unroll
    for (int k = 2; k <= 8; k <<= 1) {
#pragma unroll
        for (int j = 8; j >= 1; j >>= 1) {
            if (j > (k >> 1)) continue;
#pragma unroll
            for (int e = 0; e < 16; ++e)
                if (!(e & j)) ce(v[e], v[e ^ j], ((e & k) == 0));
        }
    }
    // ---- float phase k=16 (direction = t&1) ----
    {
        bool up16 = ((t & 1) == 0);
#pragma unroll
        for (int j = 8; j >= 1; j >>= 1)
#pragma unroll
            for (int e = 0; e < 16; ++e)
                if (!(e & j)) ce(v[e], v[e ^ j], up16);
    }

    // ---- convert to framed ordered-uint keys (frame = direction of next phase, k=32) ----
    unsigned F = (t & 2) ? 0xFFFFFFFFu : 0u;
    unsigned s_[16];
#pragma unroll
    for (int e = 0; e < 16; ++e) {
        unsigned b = __float_as_uint(v[e]);
        unsigned k = b ^ ((unsigned)((int)b >> 31) | 0x80000000u);
        s_[e] = k ^ F;
    }

    // ---- int phases m=5..14 ----
    REF(2);    slayer<1>(s_, t); ltail(s_);                                   // k=32
    REF(4);    slayer<2>(s_, t); slayer<1>(s_, t); ltail(s_);                 // k=64
    REF(8);    slayer<4>(s_, t); slayer<2>(s_, t); slayer<1>(s_, t); ltail(s_);
    REF(16);   slayer<8>(s_, t); slayer<4>(s_, t); slayer<2>(s_, t); slayer<1>(s_, t); ltail(s_);
    REF(32);   slayer<16>(s_, t); slayer<8>(s_, t); slayer<4>(s_, t); slayer<2>(s_, t); slayer<1>(s_, t); ltail(s_);
    REF(64);   slayer<32>(s_, t); slayer<16>(s_, t); slayer<8>(s_, t); slayer<4>(s_, t); slayer<2>(s_, t); slayer<1>(s_, t); ltail(s_);
    REF(128);  llayer<64>(s_, sbuf, t);
               slayer<32>(s_, t); slayer<16>(s_, t); slayer<8>(s_, t); slayer<4>(s_, t); slayer<2>(s_, t); slayer<1>(s_, t); ltail(s_);
    REF(256);  llayer<128>(s_, sbuf, t); llayer<64>(s_, sbuf, t);
               slayer<32>(s_, t); slayer<16>(s_, t); slayer<8>(s_, t); slayer<4>(s_, t); slayer<2>(s_, t); slayer<1>(s_, t); ltail(s_);
    REF(512);  llayer<256>(s_, sbuf, t); llayer<128>(s_, sbuf, t); llayer<64>(s_, sbuf, t);
               slayer<32>(s_, t); slayer<16>(s_, t); slayer<8>(s_, t); slayer<4>(s_, t); slayer<2>(s_, t); slayer<1>(s_, t); ltail(s_);
    REF(1024); llayer<512>(s_, sbuf, t); llayer<256>(s_, sbuf, t); llayer<128>(s_, sbuf, t); llayer<64>(s_, sbuf, t);
               slayer<32>(s_, t); slayer<16>(s_, t); slayer<8>(s_, t); slayer<4>(s_, t); slayer<2>(s_, t); slayer<1>(s_, t); ltail(s_);

    // ---- unframe + weighted sum: ascending pos = t*16+e, descending rank r = 16383-pos ----
    float accum = 0.f;
    const float* pwo = pw + och * 21;
#pragma unroll
    for (int e = 0; e < 16; ++e) {
        unsigned key = s_[e] ^ F;
        unsigned b = key ^ ((unsigned)((int)(~key) >> 31) | 0x80000000u);
        float val = __uint_as_float(b);
        int pos = t * 16 + e;
        int r = (L2 - 1) - pos;
        float posf = fminf((float)r / 16383.0f, 1.0f);
        float idxf = 20.0f * posf;
        int idx = (int)idxf;
        float frac = idxf - (float)idx;
        int i1 = min(idx + 1, 20);
        float wv = (1.0f - frac) * pwo[idx] + frac * pwo[i1];
        accum = fmaf(val, wv, accum);
    }
#pragma unroll
    for (int d2 = 32; d2 >= 1; d2 >>= 1) accum += __shfl_xor(accum, d2, 64);
    float* sf = (float*)sbuf;
    if ((t & 63) == 0) sf[t >> 6] = accum;
    __syncthreads();
    if (t == 0) {
        float tot = 0.f;
#pragma unroll
        for (int wv2 = 0; wv2 < 16; ++wv2) tot += sf[wv2];
        out[(size_t)n * OC + och] = tot * (1.0f / (float)L2);
    }
}

extern "C" void kernel_launch(void* const* d_in, const int* in_sizes, int n_in,
                              void* d_out, int out_size, void* d_ws, size_t ws_size,
                              hipStream_t stream) {
    const float* x    = (const float*)d_in[0];
    const float* mask = (const float*)d_in[1];
    const float* w1   = (const float*)d_in[2];
    const float* b1   = (const float*)d_in[3];
    const float* w2   = (const float*)d_in[4];
    const float* b2   = (const float*)d_in[5];
    const float* pw   = (const float*)d_in[6];
    float* out = (float*)d_out;

    float* ha = (float*)d_ws;
    float* hb = ha + (size_t)NB * DIM * LEN;
    float* y  = hb + (size_t)NB * DIM * LEN;
    size_t used = (size_t)2 * NB * DIM * LEN * sizeof(float);
    size_t perN = (size_t)OC * L2 * sizeof(float);   // 8 MB per n
    int nchunk = 1;
    if (ws_size > used + perN) {
        size_t c = (ws_size - used) / perN;
        nchunk = (int)(c > NB ? NB : c);
    }

    hipLaunchKernelGGL(kA, dim3(DIM, NB), dim3(128), 0, stream, x, mask, w1, b1, ha, hb);
    for (int base = 0; base < NB; base += nchunk) {
        int nc = nchunk < (NB - base) ? nchunk : (NB - base);
        hipLaunchKernelGGL(kB, dim3(64, nc), dim3(256), 0, stream, ha, hb, w2, b2, y, base);
        hipLaunchKernelGGL(kC, dim3(OC * nc), dim3(1024), 0, stream, y, pw, out, base);
    }
}

// Round 4
// 346.448 us; speedup vs baseline: 4.1065x; 1.4258x over previous
//
#include <hip/hip_runtime.h>
#include <hip/hip_bf16.h>

// Shapes: x:(16,32,128) mask:(16,128) w1:(256,66) b1:(256) w2:(128,256) b2:(128) pool_w:(128,21)
// L=128, L2=16384, dim=256, out_c=128. Output (16,128) f32.

#define NB 16
#define CIN 33
#define DIM 256
#define LEN 128
#define OC 128
#define L2 16384

typedef short bf16x8 __attribute__((ext_vector_type(8)));
typedef float f32x4 __attribute__((ext_vector_type(4)));

__device__ __forceinline__ unsigned short f32_to_bf16_rne(float f) {
    unsigned u = __float_as_uint(f);
    unsigned rb = ((u >> 16) & 1u) + 0x7FFFu;
    return (unsigned short)((u + rb) >> 16);
}
__device__ __forceinline__ float bf16_to_f32(unsigned short b) {
    return __uint_as_float(((unsigned)b) << 16);
}

// ---------------- kernel A: ha/hb = w1a/w1b @ xm, with b1 folded in (half each) ----------------
__global__ __launch_bounds__(128) void kA(const float* __restrict__ x,
                                          const float* __restrict__ mask,
                                          const float* __restrict__ w1,
                                          const float* __restrict__ b1,
                                          float* __restrict__ ha,
                                          float* __restrict__ hb) {
    int d = blockIdx.x;
    int n = blockIdx.y;
    int l = threadIdx.x;
    const float* w1r = w1 + d * (2 * CIN);
    float a = 0.f, b = 0.f;
#pragma unroll
    for (int c = 0; c < CIN; ++c) {
        float xv = (c < 32) ? x[((size_t)n * 32 + c) * LEN + l] : mask[(size_t)n * LEN + l];
        a = fmaf(w1r[c], xv, a);
        b = fmaf(w1r[CIN + c], xv, b);
    }
    float hb1 = 0.5f * b1[d];
    ha[((size_t)n * DIM + d) * LEN + l] = a + hb1;
    hb[((size_t)n * DIM + d) * LEN + l] = b + hb1;
}

// ---------------- kernel W: split w2 into bf16 hi/lo ----------------
__global__ __launch_bounds__(256) void kW(const float* __restrict__ w2,
                                          unsigned short* __restrict__ w2hi,
                                          unsigned short* __restrict__ w2lo) {
    int idx = blockIdx.x * 256 + threadIdx.x;   // 32768 total
    float v = w2[idx];
    unsigned short h = f32_to_bf16_rne(v);
    unsigned short l = f32_to_bf16_rne(v - bf16_to_f32(h));
    w2hi[idx] = h;
    w2lo[idx] = l;
}

// ---------------- kernel B: MFMA split-bf16 GEMM ----------------
// Per block (i0, zloc): C[o=128][j=128] = sum_d w2[o,d]*relu(ha[d,i0]+hb[d,j]) + b2[o]
// 256 threads = 4 waves. K-step 32. LDS rows padded to 40 ushorts (80B) -> <=2-way conflicts.
#define ROWP 40
__global__ __launch_bounds__(256) void kB(const float* __restrict__ ha,
                                          const float* __restrict__ hb,
                                          const unsigned short* __restrict__ w2hi,
                                          const unsigned short* __restrict__ w2lo,
                                          const float* __restrict__ b2,
                                          unsigned short* __restrict__ y,
                                          int nbase) {
    __shared__ unsigned short Wh[128 * ROWP], Wl[128 * ROWP];
    __shared__ unsigned short Bh[128 * ROWP], Bl[128 * ROWP];
    __shared__ float ha_s[DIM];
    int i0 = blockIdx.x;
    int zloc = blockIdx.y;
    int n = nbase + zloc;
    int tid = threadIdx.x;
    int wv = tid >> 6, l = tid & 63;
    int g = l >> 4, lr = l & 15;

    if (tid < DIM) ha_s[tid] = ha[((size_t)n * DIM + tid) * LEN + i0];

    // acc init with b2 (bias folded)
    f32x4 acc[2][8];
    float bv2[2][4];
#pragma unroll
    for (int mt = 0; mt < 2; ++mt)
#pragma unroll
        for (int r = 0; r < 4; ++r)
            bv2[mt][r] = b2[(wv * 2 + mt) * 16 + g * 4 + r];
#pragma unroll
    for (int mt = 0; mt < 2; ++mt)
#pragma unroll
        for (int nt = 0; nt < 8; ++nt)
#pragma unroll
            for (int r = 0; r < 4; ++r)
                acc[mt][nt][r] = bv2[mt][r];

    __syncthreads();   // ha_s ready

    for (int d0 = 0; d0 < DIM; d0 += 32) {
        // ---- stage W tile: Wh/Wl[o][k] directly from w2hi/w2lo rows ----
        {
            int o = tid & 127, hf2 = tid >> 7;             // hf2: which 16-k half
            const unsigned short* gh = w2hi + (size_t)o * DIM + d0 + hf2 * 16;
            const unsigned short* gl = w2lo + (size_t)o * DIM + d0 + hf2 * 16;
            uint4 a0 = *(const uint4*)&gh[0], a1 = *(const uint4*)&gh[8];
            uint4 c0 = *(const uint4*)&gl[0], c1 = *(const uint4*)&gl[8];
            *(uint4*)&Wh[o * ROWP + hf2 * 16] = a0;
            *(uint4*)&Wh[o * ROWP + hf2 * 16 + 8] = a1;
            *(uint4*)&Wl[o * ROWP + hf2 * 16] = c0;
            *(uint4*)&Wl[o * ROWP + hf2 * 16 + 8] = c1;
        }
        // ---- stage B tile: h^T[j][k] = relu(ha[d]+hb[d][j]) split hi/lo ----
        {
            int j = tid & 127, kh = tid >> 7;
            union { unsigned short u[16]; uint4 q[2]; } hiv, lov;
#pragma unroll
            for (int kk = 0; kk < 16; ++kk) {
                int d = d0 + kh * 16 + kk;
                float hv = fmaxf(ha_s[d] + hb[((size_t)n * DIM + d) * LEN + j], 0.f);
                unsigned short hbits = f32_to_bf16_rne(hv);
                unsigned short lbits = f32_to_bf16_rne(hv - bf16_to_f32(hbits));
                hiv.u[kk] = hbits;
                lov.u[kk] = lbits;
            }
            *(uint4*)&Bh[j * ROWP + kh * 16] = hiv.q[0];
            *(uint4*)&Bh[j * ROWP + kh * 16 + 8] = hiv.q[1];
            *(uint4*)&Bl[j * ROWP + kh * 16] = lov.q[0];
            *(uint4*)&Bl[j * ROWP + kh * 16 + 8] = lov.q[1];
        }
        __syncthreads();

        // ---- MFMA: wave wv owns M-tiles {2wv, 2wv+1}, all 8 N-tiles ----
        bf16x8 ah[2], al[2];
#pragma unroll
        for (int mt = 0; mt < 2; ++mt) {
            int row = (wv * 2 + mt) * 16 + lr;
            ah[mt] = *(bf16x8*)&Wh[row * ROWP + g * 8];
            al[mt] = *(bf16x8*)&Wl[row * ROWP + g * 8];
        }
#pragma unroll
        for (int nt = 0; nt < 8; ++nt) {
            int brow = nt * 16 + lr;
            bf16x8 bh = *(bf16x8*)&Bh[brow * ROWP + g * 8];
            bf16x8 bl = *(bf16x8*)&Bl[brow * ROWP + g * 8];
#pragma unroll
            for (int mt = 0; mt < 2; ++mt) {
                acc[mt][nt] = __builtin_amdgcn_mfma_f32_16x16x32_bf16(ah[mt], bh, acc[mt][nt], 0, 0, 0);
                acc[mt][nt] = __builtin_amdgcn_mfma_f32_16x16x32_bf16(ah[mt], bl, acc[mt][nt], 0, 0, 0);
                acc[mt][nt] = __builtin_amdgcn_mfma_f32_16x16x32_bf16(al[mt], bh, acc[mt][nt], 0, 0, 0);
            }
        }
        __syncthreads();
    }

    // ---- epilogue: store bf16 y ----
#pragma unroll
    for (int mt = 0; mt < 2; ++mt)
#pragma unroll
        for (int nt = 0; nt < 8; ++nt)
#pragma unroll
            for (int r = 0; r < 4; ++r) {
                int o = (wv * 2 + mt) * 16 + g * 4 + r;
                int col = nt * 16 + lr;
                y[((size_t)zloc * OC + o) * L2 + (size_t)i0 * LEN + col] =
                    f32_to_bf16_rne(acc[mt][nt][r]);
            }
}

// ---------------- kernel C: registerized bitonic sort on bf16-derived keys ----------
__device__ __forceinline__ unsigned umn(unsigned a, unsigned b) { return a < b ? a : b; }
__device__ __forceinline__ unsigned umx(unsigned a, unsigned b) { return a > b ? a : b; }

template<int D>
__device__ __forceinline__ unsigned xg(unsigned x) {
    if constexpr (D == 1)
        return (unsigned)__builtin_amdgcn_mov_dpp((int)x, 0xB1, 0xF, 0xF, false);
    else if constexpr (D == 2)
        return (unsigned)__builtin_amdgcn_mov_dpp((int)x, 0x4E, 0xF, 0xF, false);
    else if constexpr (D == 4) {
        int y = __builtin_amdgcn_mov_dpp((int)x, 0x141, 0xF, 0xF, false);
        return (unsigned)__builtin_amdgcn_mov_dpp(y, 0x1B, 0xF, 0xF, false);
    } else if constexpr (D == 8) {
        int y = __builtin_amdgcn_mov_dpp((int)x, 0x140, 0xF, 0xF, false);
        return (unsigned)__builtin_amdgcn_mov_dpp(y, 0x141, 0xF, 0xF, false);
    } else if constexpr (D == 16)
        return (unsigned)__builtin_amdgcn_ds_swizzle((int)x, 0x401F);
    else
        return (unsigned)__shfl_xor((int)x, D, 64);
}

template<int D>
__device__ __forceinline__ void slayer(unsigned* s, int t) {
    const bool up_sel = (t & D) != 0;
#pragma unroll
    for (int e = 0; e < 16; ++e) {
        unsigned pv = xg<D>(s[e]);
        unsigned mn = umn(s[e], pv), mx = umx(s[e], pv);
        s[e] = up_sel ? mx : mn;
    }
}

__device__ __forceinline__ void ltail(unsigned* s) {
#pragma unroll
    for (int j = 8; j >= 1; j >>= 1)
#pragma unroll
        for (int e = 0; e < 16; ++e)
            if (!(e & j)) {
                unsigned a = s[e], b = s[e ^ j];
                s[e] = umn(a, b);
                s[e ^ j] = umx(a, b);
            }
}

template<int D>
__device__ __forceinline__ void llayer(unsigned* s, unsigned* lds, int t) {
    const bool up_sel = (t & D) != 0;
    const int p = t ^ D;
#pragma unroll
    for (int h = 0; h < 2; ++h) {
        uint4* wp = (uint4*)&lds[t * 12];
        wp[0] = make_uint4(s[h * 8 + 0], s[h * 8 + 1], s[h * 8 + 2], s[h * 8 + 3]);
        wp[1] = make_uint4(s[h * 8 + 4], s[h * 8 + 5], s[h * 8 + 6], s[h * 8 + 7]);
        __syncthreads();
        const uint4* rp = (const uint4*)&lds[p * 12];
        uint4 r0 = rp[0], r1 = rp[1];
        unsigned pe[8] = {r0.x, r0.y, r0.z, r0.w, r1.x, r1.y, r1.z, r1.w};
#pragma unroll
        for (int c = 0; c < 8; ++c) {
            unsigned a = s[h * 8 + c], b = pe[c];
            unsigned mn = umn(a, b), mx = umx(a, b);
            s[h * 8 + c] = up_sel ? mx : mn;
        }
        __syncthreads();
    }
}

#define REF(KS)                                         \
    {                                                   \
        unsigned nf = (t & (KS)) ? 0xFFFFFFFFu : 0u;    \
        unsigned dx = nf ^ F;                           \
        _Pragma("unroll") for (int e = 0; e < 16; ++e) s_[e] ^= dx; \
        F = nf;                                         \
    }

#define LLOC(J)                                         \
    _Pragma("unroll") for (int e = 0; e < 16; ++e)      \
        if (!(e & (J))) {                               \
            unsigned a = s_[e], b = s_[e ^ (J)];        \
            s_[e] = umn(a, b);                          \
            s_[e ^ (J)] = umx(a, b);                    \
        }

__global__ __launch_bounds__(1024, 8) void kC(const unsigned short* __restrict__ y,
                                              const float* __restrict__ pw,
                                              float* __restrict__ out,
                                              int nbase) {
    __shared__ unsigned sbuf[1024 * 12];   // 48 KB
    int row = blockIdx.x;
    int och = row & (OC - 1);
    int n = nbase + (row >> 7);
    int t = threadIdx.x;
    const unsigned short* yr = y + (size_t)row * L2;

    union { uint4 q[2]; unsigned short u[16]; } ld;
    ld.q[0] = *(const uint4*)&yr[t * 16];
    ld.q[1] = *(const uint4*)&yr[t * 16 + 8];

    // framed ordered-uint keys: key = ordify16(bf16)<<16, frame for phase k=2
    unsigned s_[16];
#pragma unroll
    for (int e = 0; e < 16; ++e) {
        unsigned u = ld.u[e];
        unsigned k16 = u ^ ((u & 0x8000u) ? 0xFFFFu : 0x8000u);
        s_[e] = (k16 << 16) ^ ((e & 2) ? 0xFFFFFFFFu : 0u);
    }

    // head phases, all ascending in framed space
    LLOC(1);                                                       // k=2
#pragma unroll
    for (int e = 0; e < 16; ++e)
        s_[e] ^= (((e & 2) ? 0xFFFFFFFFu : 0u) ^ ((e & 4) ? 0xFFFFFFFFu : 0u));
    LLOC(2); LLOC(1);                                              // k=4
#pragma unroll
    for (int e = 0; e < 16; ++e)
        s_[e] ^= (((e & 4) ? 0xFFFFFFFFu : 0u) ^ ((e & 8) ? 0xFFFFFFFFu : 0u));
    LLOC(4); LLOC(2); LLOC(1);                                     // k=8
    unsigned F = (t & 1) ? 0xFFFFFFFFu : 0u;
#pragma unroll
    for (int e = 0; e < 16; ++e)
        s_[e] ^= (((e & 8) ? 0xFFFFFFFFu : 0u) ^ F);
    LLOC(8); LLOC(4); LLOC(2); LLOC(1);                            // k=16

    // main phases k=32..16384
    REF(2);    slayer<1>(s_, t); ltail(s_);
    REF(4);    slayer<2>(s_, t); slayer<1>(s_, t); ltail(s_);
    REF(8);    slayer<4>(s_, t); slayer<2>(s_, t); slayer<1>(s_, t); ltail(s_);
    REF(16);   slayer<8>(s_, t); slayer<4>(s_, t); slayer<2>(s_, t); slayer<1>(s_, t); ltail(s_);
    REF(32);   slayer<16>(s_, t); slayer<8>(s_, t); slayer<4>(s_, t); slayer<2>(s_, t); slayer<1>(s_, t); ltail(s_);
    REF(64);   slayer<32>(s_, t); slayer<16>(s_, t); slayer<8>(s_, t); slayer<4>(s_, t); slayer<2>(s_, t); slayer<1>(s_, t); ltail(s_);
    REF(128);  llayer<64>(s_, sbuf, t);
               slayer<32>(s_, t); slayer<16>(s_, t); slayer<8>(s_, t); slayer<4>(s_, t); slayer<2>(s_, t); slayer<1>(s_, t); ltail(s_);
    REF(256);  llayer<128>(s_, sbuf, t); llayer<64>(s_, sbuf, t);
               slayer<32>(s_, t); slayer<16>(s_, t); slayer<8>(s_, t); slayer<4>(s_, t); slayer<2>(s_, t); slayer<1>(s_, t); ltail(s_);
    REF(512);  llayer<256>(s_, sbuf, t); llayer<128>(s_, sbuf, t); llayer<64>(s_, sbuf, t);
               slayer<32>(s_, t); slayer<16>(s_, t); slayer<8>(s_, t); slayer<4>(s_, t); slayer<2>(s_, t); slayer<1>(s_, t); ltail(s_);
    REF(1024); llayer<512>(s_, sbuf, t); llayer<256>(s_, sbuf, t); llayer<128>(s_, sbuf, t); llayer<64>(s_, sbuf, t);
               slayer<32>(s_, t); slayer<16>(s_, t); slayer<8>(s_, t); slayer<4>(s_, t); slayer<2>(s_, t); slayer<1>(s_, t); ltail(s_);

    // unframe + reconstruct bf16 value + weighted sum (asc pos -> desc rank)
    float accum = 0.f;
    const float* pwo = pw + och * 21;
#pragma unroll
    for (int e = 0; e < 16; ++e) {
        unsigned k16 = (s_[e] ^ F) >> 16;
        unsigned b16 = k16 ^ ((k16 & 0x8000u) ? 0x8000u : 0xFFFFu);
        float val = __uint_as_float(b16 << 16);
        int pos = t * 16 + e;
        int r = (L2 - 1) - pos;
        float posf = fminf((float)r / 16383.0f, 1.0f);
        float idxf = 20.0f * posf;
        int idx = (int)idxf;
        float frac = idxf - (float)idx;
        int i1 = min(idx + 1, 20);
        float wv = (1.0f - frac) * pwo[idx] + frac * pwo[i1];
        accum = fmaf(val, wv, accum);
    }
#pragma unroll
    for (int d2 = 32; d2 >= 1; d2 >>= 1) accum += __shfl_xor(accum, d2, 64);
    float* sf = (float*)sbuf;
    if ((t & 63) == 0) sf[t >> 6] = accum;
    __syncthreads();
    if (t == 0) {
        float tot = 0.f;
#pragma unroll
        for (int wv2 = 0; wv2 < 16; ++wv2) tot += sf[wv2];
        out[(size_t)n * OC + och] = tot * (1.0f / (float)L2);
    }
}

extern "C" void kernel_launch(void* const* d_in, const int* in_sizes, int n_in,
                              void* d_out, int out_size, void* d_ws, size_t ws_size,
                              hipStream_t stream) {
    const float* x    = (const float*)d_in[0];
    const float* mask = (const float*)d_in[1];
    const float* w1   = (const float*)d_in[2];
    const float* b1   = (const float*)d_in[3];
    const float* w2   = (const float*)d_in[4];
    const float* b2   = (const float*)d_in[5];
    const float* pw   = (const float*)d_in[6];
    float* out = (float*)d_out;

    char* ws = (char*)d_ws;
    float* ha = (float*)ws;                                       // 2 MB
    float* hb = ha + (size_t)NB * DIM * LEN;                      // 2 MB
    unsigned short* w2hi = (unsigned short*)(ws + (size_t)2 * NB * DIM * LEN * 4);  // 64 KB
    unsigned short* w2lo = w2hi + (size_t)OC * DIM;                                  // 64 KB
    unsigned short* y = w2lo + (size_t)OC * DIM;                  // up to 64 MB bf16

    size_t used = (size_t)2 * NB * DIM * LEN * 4 + (size_t)2 * OC * DIM * 2;
    size_t perN = (size_t)OC * L2 * 2;   // 4 MB per n (bf16)
    int nchunk = 1;
    if (ws_size > used + perN) {
        size_t c = (ws_size - used) / perN;
        nchunk = (int)(c > NB ? NB : c);
    }

    hipLaunchKernelGGL(kA, dim3(DIM, NB), dim3(128), 0, stream, x, mask, w1, b1, ha, hb);
    hipLaunchKernelGGL(kW, dim3(OC * DIM / 256), dim3(256), 0, stream, w2, w2hi, w2lo);
    for (int base = 0; base < NB; base += nchunk) {
        int nc = nchunk < (NB - base) ? nchunk : (NB - base);
        hipLaunchKernelGGL(kB, dim3(LEN, nc), dim3(256), 0, stream, ha, hb, w2hi, w2lo, b2, y, base);
        hipLaunchKernelGGL(kC, dim3(OC * nc), dim3(1024), 0, stream, y, pw, out, base);
    }
}

// Round 5
// 291.754 us; speedup vs baseline: 4.8763x; 1.1875x over previous
//
#include <hip/hip_runtime.h>
#include <hip/hip_bf16.h>

// Shapes: x:(16,32,128) mask:(16,128) w1:(256,66) b1:(256) w2:(128,256) b2:(128) pool_w:(128,21)
// L=128, L2=16384, dim=256, out_c=128. Output (16,128) f32.

#define NB 16
#define CIN 33
#define DIM 256
#define LEN 128
#define OC 128
#define L2 16384

typedef short bf16x8 __attribute__((ext_vector_type(8)));
typedef float f32x4 __attribute__((ext_vector_type(4)));

__device__ __forceinline__ unsigned short f32_to_bf16_rne(float f) {
    unsigned u = __float_as_uint(f);
    unsigned rb = ((u >> 16) & 1u) + 0x7FFFu;
    return (unsigned short)((u + rb) >> 16);
}
__device__ __forceinline__ float bf16_to_f32(unsigned short b) {
    return __uint_as_float(((unsigned)b) << 16);
}

// ---------------- kernel A: ha/hb = w1a/w1b @ xm, with b1 folded in (half each) ----------------
__global__ __launch_bounds__(128) void kA(const float* __restrict__ x,
                                          const float* __restrict__ mask,
                                          const float* __restrict__ w1,
                                          const float* __restrict__ b1,
                                          float* __restrict__ ha,
                                          float* __restrict__ hb) {
    int d = blockIdx.x;
    int n = blockIdx.y;
    int l = threadIdx.x;
    const float* w1r = w1 + d * (2 * CIN);
    float a = 0.f, b = 0.f;
#pragma unroll
    for (int c = 0; c < CIN; ++c) {
        float xv = (c < 32) ? x[((size_t)n * 32 + c) * LEN + l] : mask[(size_t)n * LEN + l];
        a = fmaf(w1r[c], xv, a);
        b = fmaf(w1r[CIN + c], xv, b);
    }
    float hb1 = 0.5f * b1[d];
    ha[((size_t)n * DIM + d) * LEN + l] = a + hb1;
    hb[((size_t)n * DIM + d) * LEN + l] = b + hb1;
}

// ---------------- kernel W: split w2 into bf16 hi/lo ----------------
__global__ __launch_bounds__(256) void kW(const float* __restrict__ w2,
                                          unsigned short* __restrict__ w2hi,
                                          unsigned short* __restrict__ w2lo) {
    int idx = blockIdx.x * 256 + threadIdx.x;   // 32768 total
    float v = w2[idx];
    unsigned short h = f32_to_bf16_rne(v);
    unsigned short l = f32_to_bf16_rne(v - bf16_to_f32(h));
    w2hi[idx] = h;
    w2lo[idx] = l;
}

// ---------------- kernel B: MFMA split-bf16 GEMM ----------------
#define ROWP 40
__global__ __launch_bounds__(256) void kB(const float* __restrict__ ha,
                                          const float* __restrict__ hb,
                                          const unsigned short* __restrict__ w2hi,
                                          const unsigned short* __restrict__ w2lo,
                                          const float* __restrict__ b2,
                                          unsigned short* __restrict__ y,
                                          int nbase) {
    __shared__ unsigned short Wh[128 * ROWP], Wl[128 * ROWP];
    __shared__ unsigned short Bh[128 * ROWP], Bl[128 * ROWP];
    __shared__ float ha_s[DIM];
    int i0 = blockIdx.x;
    int zloc = blockIdx.y;
    int n = nbase + zloc;
    int tid = threadIdx.x;
    int wv = tid >> 6, l = tid & 63;
    int g = l >> 4, lr = l & 15;

    if (tid < DIM) ha_s[tid] = ha[((size_t)n * DIM + tid) * LEN + i0];

    f32x4 acc[2][8];
    float bv2[2][4];
#pragma unroll
    for (int mt = 0; mt < 2; ++mt)
#pragma unroll
        for (int r = 0; r < 4; ++r)
            bv2[mt][r] = b2[(wv * 2 + mt) * 16 + g * 4 + r];
#pragma unroll
    for (int mt = 0; mt < 2; ++mt)
#pragma unroll
        for (int nt = 0; nt < 8; ++nt)
#pragma unroll
            for (int r = 0; r < 4; ++r)
                acc[mt][nt][r] = bv2[mt][r];

    __syncthreads();

    for (int d0 = 0; d0 < DIM; d0 += 32) {
        {
            int o = tid & 127, hf2 = tid >> 7;
            const unsigned short* gh = w2hi + (size_t)o * DIM + d0 + hf2 * 16;
            const unsigned short* gl = w2lo + (size_t)o * DIM + d0 + hf2 * 16;
            uint4 a0 = *(const uint4*)&gh[0], a1 = *(const uint4*)&gh[8];
            uint4 c0 = *(const uint4*)&gl[0], c1 = *(const uint4*)&gl[8];
            *(uint4*)&Wh[o * ROWP + hf2 * 16] = a0;
            *(uint4*)&Wh[o * ROWP + hf2 * 16 + 8] = a1;
            *(uint4*)&Wl[o * ROWP + hf2 * 16] = c0;
            *(uint4*)&Wl[o * ROWP + hf2 * 16 + 8] = c1;
        }
        {
            int j = tid & 127, kh = tid >> 7;
            union { unsigned short u[16]; uint4 q[2]; } hiv, lov;
#pragma unroll
            for (int kk = 0; kk < 16; ++kk) {
                int d = d0 + kh * 16 + kk;
                float hv = fmaxf(ha_s[d] + hb[((size_t)n * DIM + d) * LEN + j], 0.f);
                unsigned short hbits = f32_to_bf16_rne(hv);
                unsigned short lbits = f32_to_bf16_rne(hv - bf16_to_f32(hbits));
                hiv.u[kk] = hbits;
                lov.u[kk] = lbits;
            }
            *(uint4*)&Bh[j * ROWP + kh * 16] = hiv.q[0];
            *(uint4*)&Bh[j * ROWP + kh * 16 + 8] = hiv.q[1];
            *(uint4*)&Bl[j * ROWP + kh * 16] = lov.q[0];
            *(uint4*)&Bl[j * ROWP + kh * 16 + 8] = lov.q[1];
        }
        __syncthreads();

        bf16x8 ah[2], al[2];
#pragma unroll
        for (int mt = 0; mt < 2; ++mt) {
            int rowi = (wv * 2 + mt) * 16 + lr;
            ah[mt] = *(bf16x8*)&Wh[rowi * ROWP + g * 8];
            al[mt] = *(bf16x8*)&Wl[rowi * ROWP + g * 8];
        }
#pragma unroll
        for (int nt = 0; nt < 8; ++nt) {
            int brow = nt * 16 + lr;
            bf16x8 bh = *(bf16x8*)&Bh[brow * ROWP + g * 8];
            bf16x8 bl = *(bf16x8*)&Bl[brow * ROWP + g * 8];
#pragma unroll
            for (int mt = 0; mt < 2; ++mt) {
                acc[mt][nt] = __builtin_amdgcn_mfma_f32_16x16x32_bf16(ah[mt], bh, acc[mt][nt], 0, 0, 0);
                acc[mt][nt] = __builtin_amdgcn_mfma_f32_16x16x32_bf16(ah[mt], bl, acc[mt][nt], 0, 0, 0);
                acc[mt][nt] = __builtin_amdgcn_mfma_f32_16x16x32_bf16(al[mt], bh, acc[mt][nt], 0, 0, 0);
            }
        }
        __syncthreads();
    }

#pragma unroll
    for (int mt = 0; mt < 2; ++mt)
#pragma unroll
        for (int nt = 0; nt < 8; ++nt)
#pragma unroll
            for (int r = 0; r < 4; ++r) {
                int o = (wv * 2 + mt) * 16 + g * 4 + r;
                int col = nt * 16 + lr;
                y[((size_t)zloc * OC + o) * L2 + (size_t)i0 * LEN + col] =
                    f32_to_bf16_rne(acc[mt][nt][r]);
            }
}

// ---------------- kernel C: histogram-rank pooling (no sort) ----------------
// 32K bins (ordified bf16 >> 1), packed 2 x u16 counts per u32 word = 64 KB LDS.
// rank weights applied via closed-form prefix W(r) of the piecewise-linear w(r).
__device__ __forceinline__ int idx_ref(int q) {
    float posf = fminf((float)q / 16383.0f, 1.0f);   // exact f32 replication of reference
    return (int)(20.0f * posf);
}

__global__ __launch_bounds__(1024) void kC(const unsigned short* __restrict__ y,
                                           const float* __restrict__ pw,
                                           float* __restrict__ out,
                                           int nbase) {
    extern __shared__ unsigned hist[];   // 16384 words = 64 KB
    // scratch layout (valid only after bins pulled to registers):
    const int QB = 0;     // int qb[21]
    const int WCW = 32;   // double Wc[21]  (words 32..73, 8B aligned)
    const int PWC = 80;   // float pwc[21]
    const int WT = 128;   // int wave totals[16]
    const int WO = 160;   // int wave excl offsets[16]
    const int CT = 256;   // double contrib[16] (words 256..287)

    int row = blockIdx.x;
    int och = row & (OC - 1);
    int n = nbase + (row >> 7);
    int t = threadIdx.x;
    int lane = t & 63, wv = t >> 6;
    const unsigned short* yr = y + (size_t)row * L2;

    // 1. zero histogram
#pragma unroll
    for (int q = 0; q < 4; ++q)
        *(uint4*)&hist[t * 16 + q * 4] = make_uint4(0, 0, 0, 0);
    __syncthreads();

    // 2. load 16 bf16 keys, ordify, packed LDS atomics
    union { uint4 q[2]; unsigned short u[16]; } ld;
    ld.q[0] = *(const uint4*)&yr[t * 16];
    ld.q[1] = *(const uint4*)&yr[t * 16 + 8];
#pragma unroll
    for (int e = 0; e < 16; ++e) {
        unsigned u = ld.u[e];
        unsigned k16 = u ^ ((u & 0x8000u) ? 0xFFFFu : 0x8000u);
        unsigned bin = k16 >> 1;                         // 15-bit bin
        atomicAdd(&hist[bin >> 1], (bin & 1) ? 0x10000u : 1u);
    }
    __syncthreads();

    // 3. pull own 16 words (bins [t*32, t*32+32)) to registers; local total
    unsigned wreg[16];
#pragma unroll
    for (int q = 0; q < 4; ++q) {
        uint4 v4 = *(const uint4*)&hist[t * 16 + q * 4];
        wreg[q * 4 + 0] = v4.x; wreg[q * 4 + 1] = v4.y;
        wreg[q * 4 + 2] = v4.z; wreg[q * 4 + 3] = v4.w;
    }
    int Ti = 0;
#pragma unroll
    for (int q2 = 0; q2 < 16; ++q2)
        Ti += (int)(wreg[q2] & 0xFFFFu) + (int)(wreg[q2] >> 16);
    __syncthreads();   // all bins in registers; hist becomes scratch

    // 4a. piece boundaries (f32-exact) + pw copy
    if (t < 21) {
        int p = t, qg;
        if (p == 0) qg = 0;
        else {
            qg = (int)((16383.0 * p + 19.0) / 20.0);
            if (qg < 1) qg = 1;
            if (qg > 16383) qg = 16383;
            while (qg > 0 && idx_ref(qg - 1) >= p) --qg;
            while (qg < 16383 && idx_ref(qg) < p) ++qg;
        }
        ((int*)hist)[QB + p] = qg;
        ((float*)hist)[PWC + p] = pw[och * 21 + p];
    }
    // 4b. wave-inclusive scan of Ti
    int incl = Ti;
#pragma unroll
    for (int d = 1; d < 64; d <<= 1) {
        int u2 = __shfl_up(incl, d, 64);
        if (lane >= d) incl += u2;
    }
    if (lane == 63) ((int*)hist)[WT + wv] = incl;
    __syncthreads();

    // 5. thread 0: wave exclusive offsets + cumulative piece sums Wc (double)
    if (t == 0) {
        int run = 0;
#pragma unroll
        for (int k = 0; k < 16; ++k) {
            int tv = ((int*)hist)[WT + k];
            ((int*)hist)[WO + k] = run;
            run += tv;
        }
        double* Wc = (double*)&hist[WCW];
        const int* qbp = (const int*)&hist[QB];
        const float* pwcp = (const float*)&hist[PWC];
        double acc = 0.0;
        for (int p = 0; p < 21; ++p) {
            Wc[p] = acc;
            int qa = qbp[p];
            int qe = (p == 20) ? L2 : qbp[p + 1];
            int N = qe - qa;
            double dp = (p < 20) ? ((double)pwcp[p + 1] - (double)pwcp[p]) : 0.0;
            long long sq = ((long long)(qa + qe - 1) * (long long)N) >> 1;   // exact (always even)
            double fr = (20.0 / 16383.0) * (double)sq - (double)p * (double)N;
            acc += (double)N * (double)pwcp[p] + dp * fr;
        }
    }
    __syncthreads();

    // 6. per-bin contributions: val * (W(G+c) - W(G)), chained W evals
    const int* qb = (const int*)&hist[QB];
    const double* Wc = (const double*)&hist[WCW];
    const float* pwc = (const float*)&hist[PWC];
    int Ei = ((const int*)hist)[WO + wv] + (incl - Ti);
    int running = Ei;
    double contrib = 0.0;

    auto evalW = [&](int r) -> double {
        if (r <= 0) return 0.0;
        int p = (int)(20.0f * (float)r * (1.0f / 16383.0f));
        if (p > 20) p = 20;
        while (p > 0 && r < qb[p]) --p;
        while (p < 20 && r >= qb[p + 1]) ++p;
        int qa = qb[p];
        int N = r - qa;
        double dp = (p < 20) ? ((double)pwc[p + 1] - (double)pwc[p]) : 0.0;
        long long sq = ((long long)(qa + r - 1) * (long long)N) >> 1;        // exact (always even)
        double fr = (20.0 / 16383.0) * (double)sq - (double)p * (double)N;
        return Wc[p] + (double)N * (double)pwc[p] + dp * fr;
    };

    double Wprev = evalW(L2 - running);
#pragma unroll
    for (int wq = 0; wq < 16; ++wq) {
        int binbase = t * 32 + wq * 2;
#pragma unroll
        for (int h = 0; h < 2; ++h) {
            int c = (h == 0) ? (int)(wreg[wq] & 0xFFFFu) : (int)(wreg[wq] >> 16);
            if (c > 0) {
                int G = L2 - running - c;
                double Wg = evalW(G);
                int bin = binbase + h;
                unsigned k0 = (unsigned)(bin << 1), k1 = k0 + 1;
                unsigned b0 = (k0 & 0x8000u) ? (k0 ^ 0x8000u) : (k0 ^ 0xFFFFu);
                unsigned b1u = (k1 & 0x8000u) ? (k1 ^ 0x8000u) : (k1 ^ 0xFFFFu);
                float v0 = __uint_as_float(b0 << 16);
                float v1 = __uint_as_float(b1u << 16);
                double valv = 0.5 * ((double)v0 + (double)v1);   // bin midpoint
                contrib += valv * (Wprev - Wg);
                Wprev = Wg;
                running += c;
            }
        }
    }

    // 7. block reduce
#pragma unroll
    for (int d = 32; d >= 1; d >>= 1) contrib += __shfl_xor(contrib, d, 64);
    if (lane == 0) ((double*)&hist[CT])[wv] = contrib;
    __syncthreads();
    if (t == 0) {
        double tot = 0.0;
#pragma unroll
        for (int k = 0; k < 16; ++k) tot += ((const double*)&hist[CT])[k];
        out[(size_t)n * OC + och] = (float)(tot * (1.0 / (double)L2));
    }
}

extern "C" void kernel_launch(void* const* d_in, const int* in_sizes, int n_in,
                              void* d_out, int out_size, void* d_ws, size_t ws_size,
                              hipStream_t stream) {
    const float* x    = (const float*)d_in[0];
    const float* mask = (const float*)d_in[1];
    const float* w1   = (const float*)d_in[2];
    const float* b1   = (const float*)d_in[3];
    const float* w2   = (const float*)d_in[4];
    const float* b2   = (const float*)d_in[5];
    const float* pw   = (const float*)d_in[6];
    float* out = (float*)d_out;

    char* ws = (char*)d_ws;
    float* ha = (float*)ws;                                       // 2 MB
    float* hb = ha + (size_t)NB * DIM * LEN;                      // 2 MB
    unsigned short* w2hi = (unsigned short*)(ws + (size_t)2 * NB * DIM * LEN * 4);  // 64 KB
    unsigned short* w2lo = w2hi + (size_t)OC * DIM;                                  // 64 KB
    unsigned short* y = w2lo + (size_t)OC * DIM;                  // up to 64 MB bf16

    size_t used = (size_t)2 * NB * DIM * LEN * 4 + (size_t)2 * OC * DIM * 2;
    size_t perN = (size_t)OC * L2 * 2;   // 4 MB per n (bf16)
    int nchunk = 1;
    if (ws_size > used + perN) {
        size_t c = (ws_size - used) / perN;
        nchunk = (int)(c > NB ? NB : c);
    }

    hipLaunchKernelGGL(kA, dim3(DIM, NB), dim3(128), 0, stream, x, mask, w1, b1, ha, hb);
    hipLaunchKernelGGL(kW, dim3(OC * DIM / 256), dim3(256), 0, stream, w2, w2hi, w2lo);
    for (int base = 0; base < NB; base += nchunk) {
        int nc = nchunk < (NB - base) ? nchunk : (NB - base);
        hipLaunchKernelGGL(kB, dim3(LEN, nc), dim3(256), 0, stream, ha, hb, w2hi, w2lo, b2, y, base);
        hipLaunchKernelGGL(kC, dim3(OC * nc), dim3(1024), 65536, stream, y, pw, out, base);
    }
}

// Round 7
// 221.923 us; speedup vs baseline: 6.4107x; 1.3147x over previous
//
#include <hip/hip_runtime.h>
#include <hip/hip_bf16.h>

// Shapes: x:(16,32,128) mask:(16,128) w1:(256,66) b1:(256) w2:(128,256) b2:(128) pool_w:(128,21)
// L=128, L2=16384, dim=256, out_c=128. Output (16,128) f32.

#define NB 16
#define CIN 33
#define DIM 256
#define LEN 128
#define OC 128
#define L2 16384

typedef short bf16x8 __attribute__((ext_vector_type(8)));
typedef float f32x4 __attribute__((ext_vector_type(4)));

__device__ __forceinline__ unsigned short f32_to_bf16_rne(float f) {
    unsigned u = __float_as_uint(f);
    unsigned rb = ((u >> 16) & 1u) + 0x7FFFu;
    return (unsigned short)((u + rb) >> 16);
}
__device__ __forceinline__ float bf16_to_f32(unsigned short b) {
    return __uint_as_float(((unsigned)b) << 16);
}

// ---------------- kernel A: ha/hb = w1a/w1b @ xm, with b1 folded in (half each) ----------------
__global__ __launch_bounds__(128) void kA(const float* __restrict__ x,
                                          const float* __restrict__ mask,
                                          const float* __restrict__ w1,
                                          const float* __restrict__ b1,
                                          float* __restrict__ ha,
                                          float* __restrict__ hb) {
    int d = blockIdx.x;
    int n = blockIdx.y;
    int l = threadIdx.x;
    const float* w1r = w1 + d * (2 * CIN);
    float a = 0.f, b = 0.f;
#pragma unroll
    for (int c = 0; c < CIN; ++c) {
        float xv = (c < 32) ? x[((size_t)n * 32 + c) * LEN + l] : mask[(size_t)n * LEN + l];
        a = fmaf(w1r[c], xv, a);
        b = fmaf(w1r[CIN + c], xv, b);
    }
    float hb1 = 0.5f * b1[d];
    ha[((size_t)n * DIM + d) * LEN + l] = a + hb1;
    hb[((size_t)n * DIM + d) * LEN + l] = b + hb1;
}

// ---------------- kernel W: split w2 into bf16 hi/lo ----------------
__global__ __launch_bounds__(256) void kW(const float* __restrict__ w2,
                                          unsigned short* __restrict__ w2hi,
                                          unsigned short* __restrict__ w2lo) {
    int idx = blockIdx.x * 256 + threadIdx.x;   // 32768 total
    float v = w2[idx];
    unsigned short h = f32_to_bf16_rne(v);
    unsigned short l = f32_to_bf16_rne(v - bf16_to_f32(h));
    w2hi[idx] = h;
    w2lo[idx] = l;
}

// ---------------- kernel B: MFMA split-bf16 GEMM ----------------
#define ROWP 40
__global__ __launch_bounds__(256) void kB(const float* __restrict__ ha,
                                          const float* __restrict__ hb,
                                          const unsigned short* __restrict__ w2hi,
                                          const unsigned short* __restrict__ w2lo,
                                          const float* __restrict__ b2,
                                          unsigned short* __restrict__ y,
                                          int nbase) {
    __shared__ unsigned short Wh[128 * ROWP], Wl[128 * ROWP];
    __shared__ unsigned short Bh[128 * ROWP], Bl[128 * ROWP];
    __shared__ float ha_s[DIM];
    int i0 = blockIdx.x;
    int zloc = blockIdx.y;
    int n = nbase + zloc;
    int tid = threadIdx.x;
    int wv = tid >> 6, l = tid & 63;
    int g = l >> 4, lr = l & 15;

    if (tid < DIM) ha_s[tid] = ha[((size_t)n * DIM + tid) * LEN + i0];

    f32x4 acc[2][8];
    float bv2[2][4];
#pragma unroll
    for (int mt = 0; mt < 2; ++mt)
#pragma unroll
        for (int r = 0; r < 4; ++r)
            bv2[mt][r] = b2[(wv * 2 + mt) * 16 + g * 4 + r];
#pragma unroll
    for (int mt = 0; mt < 2; ++mt)
#pragma unroll
        for (int nt = 0; nt < 8; ++nt)
#pragma unroll
            for (int r = 0; r < 4; ++r)
                acc[mt][nt][r] = bv2[mt][r];

    __syncthreads();

    for (int d0 = 0; d0 < DIM; d0 += 32) {
        {
            int o = tid & 127, hf2 = tid >> 7;
            const unsigned short* gh = w2hi + (size_t)o * DIM + d0 + hf2 * 16;
            const unsigned short* gl = w2lo + (size_t)o * DIM + d0 + hf2 * 16;
            uint4 a0 = *(const uint4*)&gh[0], a1 = *(const uint4*)&gh[8];
            uint4 c0 = *(const uint4*)&gl[0], c1 = *(const uint4*)&gl[8];
            *(uint4*)&Wh[o * ROWP + hf2 * 16] = a0;
            *(uint4*)&Wh[o * ROWP + hf2 * 16 + 8] = a1;
            *(uint4*)&Wl[o * ROWP + hf2 * 16] = c0;
            *(uint4*)&Wl[o * ROWP + hf2 * 16 + 8] = c1;
        }
        {
            int j = tid & 127, kh = tid >> 7;
            union { unsigned short u[16]; uint4 q[2]; } hiv, lov;
#pragma unroll
            for (int kk = 0; kk < 16; ++kk) {
                int d = d0 + kh * 16 + kk;
                float hv = fmaxf(ha_s[d] + hb[((size_t)n * DIM + d) * LEN + j], 0.f);
                unsigned short hbits = f32_to_bf16_rne(hv);
                unsigned short lbits = f32_to_bf16_rne(hv - bf16_to_f32(hbits));
                hiv.u[kk] = hbits;
                lov.u[kk] = lbits;
            }
            *(uint4*)&Bh[j * ROWP + kh * 16] = hiv.q[0];
            *(uint4*)&Bh[j * ROWP + kh * 16 + 8] = hiv.q[1];
            *(uint4*)&Bl[j * ROWP + kh * 16] = lov.q[0];
            *(uint4*)&Bl[j * ROWP + kh * 16 + 8] = lov.q[1];
        }
        __syncthreads();

        bf16x8 ah[2], al[2];
#pragma unroll
        for (int mt = 0; mt < 2; ++mt) {
            int rowi = (wv * 2 + mt) * 16 + lr;
            ah[mt] = *(bf16x8*)&Wh[rowi * ROWP + g * 8];
            al[mt] = *(bf16x8*)&Wl[rowi * ROWP + g * 8];
        }
#pragma unroll
        for (int nt = 0; nt < 8; ++nt) {
            int brow = nt * 16 + lr;
            bf16x8 bh = *(bf16x8*)&Bh[brow * ROWP + g * 8];
            bf16x8 bl = *(bf16x8*)&Bl[brow * ROWP + g * 8];
#pragma unroll
            for (int mt = 0; mt < 2; ++mt) {
                acc[mt][nt] = __builtin_amdgcn_mfma_f32_16x16x32_bf16(ah[mt], bh, acc[mt][nt], 0, 0, 0);
                acc[mt][nt] = __builtin_amdgcn_mfma_f32_16x16x32_bf16(ah[mt], bl, acc[mt][nt], 0, 0, 0);
                acc[mt][nt] = __builtin_amdgcn_mfma_f32_16x16x32_bf16(al[mt], bh, acc[mt][nt], 0, 0, 0);
            }
        }
        __syncthreads();
    }

#pragma unroll
    for (int mt = 0; mt < 2; ++mt)
#pragma unroll
        for (int nt = 0; nt < 8; ++nt)
#pragma unroll
            for (int r = 0; r < 4; ++r) {
                int o = (wv * 2 + mt) * 16 + g * 4 + r;
                int col = nt * 16 + lr;
                y[((size_t)zloc * OC + o) * L2 + (size_t)i0 * LEN + col] =
                    f32_to_bf16_rne(acc[mt][nt][r]);
            }
}

// ---------------- kernel C: rank-slot histogram pooling ----------------
// 32768 bins (ordified bf16 >> 1; 2 adjacent codes merged), u16 counts packed 2/word
// = 16384 words = 64 KB dynamic LDS (exactly). Phase 1: histogram via packed LDS atomics.
// Phase 2: hierarchical scan (wave shfl_up + wave totals stashed in hist words whose
// counts are already in registers) -> per-bin descending-rank start = L2 - P_incl(bin).
// Phase 3: each element atomically claims its rank slot, applies the reference's exact
// per-element f32 weight formula (pw row read from global; 84 B, L1-resident).
// Tie order within a bin is irrelevant (values identical to within 1 ulp).
__global__ __launch_bounds__(1024) void kC(const unsigned short* __restrict__ y,
                                           const float* __restrict__ pw,
                                           float* __restrict__ out,
                                           int nbase) {
    extern __shared__ unsigned hist[];   // 16384 words = 64 KB
    int row = blockIdx.x;
    int och = row & (OC - 1);
    int n = nbase + (row >> 7);
    int t = threadIdx.x;
    int lane = t & 63, wv = t >> 6;
    const unsigned short* yr = y + (size_t)row * L2;
    const float* pwo = pw + och * 21;

    // 1. zero hist: thread owns words [t*16, t*16+16)
#pragma unroll
    for (int q = 0; q < 4; ++q)
        *(uint4*)&hist[t * 16 + q * 4] = make_uint4(0, 0, 0, 0);
    __syncthreads();

    // 2. load 16 bf16, histogram. word = k16>>2 (0..16383), half = (k16>>1)&1.
    union { uint4 q[2]; unsigned short u[16]; } ld;
    ld.q[0] = *(const uint4*)&yr[t * 16];
    ld.q[1] = *(const uint4*)&yr[t * 16 + 8];
#pragma unroll
    for (int e = 0; e < 16; ++e) {
        unsigned u = ld.u[e];
        unsigned k16 = u ^ ((u & 0x8000u) ? 0xFFFFu : 0x8000u);
        atomicAdd(&hist[k16 >> 2], ((k16 >> 1) & 1) ? 0x10000u : 1u);
    }
    __syncthreads();

    // 3. scan: thread owns words [t*16, t*16+16) = bins [t*32, t*32+32), ascending
    unsigned wreg[16];
#pragma unroll
    for (int q = 0; q < 4; ++q) {
        uint4 v4 = *(const uint4*)&hist[t * 16 + q * 4];
        wreg[q * 4 + 0] = v4.x; wreg[q * 4 + 1] = v4.y;
        wreg[q * 4 + 2] = v4.z; wreg[q * 4 + 3] = v4.w;
    }
    int Ti = 0;
#pragma unroll
    for (int q = 0; q < 16; ++q)
        Ti += (int)(wreg[q] & 0xFFFFu) + (int)(wreg[q] >> 16);
    int incl = Ti;
#pragma unroll
    for (int d = 1; d < 64; d <<= 1) {
        int u2 = __shfl_up(incl, d, 64);
        if (lane >= d) incl += u2;
    }
    __syncthreads();                       // all wreg reads complete -> hist is scratch
    // stash wave totals in a word owned by lane 63 of each wave (its counts are in wreg)
    if (lane == 63) hist[t * 16] = (unsigned)incl;
    __syncthreads();
    int base = 0;
#pragma unroll
    for (int k = 0; k < 16; ++k) {
        int tw = (int)hist[(k * 64 + 63) * 16];   // same word for all threads -> broadcast
        base += (k < wv) ? tw : 0;
    }
    __syncthreads();                       // totals consumed; owners may overwrite
    int P = base + (incl - Ti);            // ascending exclusive prefix before this thread's bins

    // write back per-bin descending-rank starts: start(b) = L2 - P_incl(b)
#pragma unroll
    for (int q = 0; q < 16; ++q) {
        int clo = (int)(wreg[q] & 0xFFFFu), chi = (int)(wreg[q] >> 16);
        P += clo;
        unsigned slo = (unsigned)(L2 - P);
        P += chi;
        unsigned shi = (unsigned)(L2 - P);
        wreg[q] = slo | (shi << 16);
    }
#pragma unroll
    for (int q = 0; q < 4; ++q)
        *(uint4*)&hist[t * 16 + q * 4] =
            make_uint4(wreg[q * 4 + 0], wreg[q * 4 + 1], wreg[q * 4 + 2], wreg[q * 4 + 3]);
    __syncthreads();

    // 4. per-element: claim slot, apply reference weight formula
    float acc = 0.f;
#pragma unroll
    for (int e = 0; e < 16; ++e) {
        unsigned u = ld.u[e];
        unsigned k16 = u ^ ((u & 0x8000u) ? 0xFFFFu : 0x8000u);
        unsigned hi = (k16 >> 1) & 1;
        unsigned old = atomicAdd(&hist[k16 >> 2], hi ? 0x10000u : 1u);
        int r = (int)(hi ? (old >> 16) : (old & 0xFFFFu));
        float posf = fminf((float)r / 16383.0f, 1.0f);
        float idxf = 20.0f * posf;
        int idx = (int)idxf;
        float frac = idxf - (float)idx;
        int i1 = min(idx + 1, 20);
        float wvw = (1.0f - frac) * pwo[idx] + frac * pwo[i1];
        float val = __uint_as_float(((unsigned)u) << 16);
        acc = fmaf(val, wvw, acc);
    }

    // 5. reduce (hist free after claims; barrier-protected reuse)
#pragma unroll
    for (int d = 32; d >= 1; d >>= 1) acc += __shfl_xor(acc, d, 64);
    __syncthreads();
    if (lane == 0) ((float*)hist)[wv] = acc;
    __syncthreads();
    if (t == 0) {
        double tot = 0.0;
#pragma unroll
        for (int k = 0; k < 16; ++k) tot += (double)((const float*)hist)[k];
        out[(size_t)n * OC + och] = (float)(tot * (1.0 / (double)L2));
    }
}

extern "C" void kernel_launch(void* const* d_in, const int* in_sizes, int n_in,
                              void* d_out, int out_size, void* d_ws, size_t ws_size,
                              hipStream_t stream) {
    const float* x    = (const float*)d_in[0];
    const float* mask = (const float*)d_in[1];
    const float* w1   = (const float*)d_in[2];
    const float* b1   = (const float*)d_in[3];
    const float* w2   = (const float*)d_in[4];
    const float* b2   = (const float*)d_in[5];
    const float* pw   = (const float*)d_in[6];
    float* out = (float*)d_out;

    char* ws = (char*)d_ws;
    float* ha = (float*)ws;                                       // 2 MB
    float* hb = ha + (size_t)NB * DIM * LEN;                      // 2 MB
    unsigned short* w2hi = (unsigned short*)(ws + (size_t)2 * NB * DIM * LEN * 4);  // 64 KB
    unsigned short* w2lo = w2hi + (size_t)OC * DIM;                                  // 64 KB
    unsigned short* y = w2lo + (size_t)OC * DIM;                  // up to 64 MB bf16

    size_t used = (size_t)2 * NB * DIM * LEN * 4 + (size_t)2 * OC * DIM * 2;
    size_t perN = (size_t)OC * L2 * 2;   // 4 MB per n (bf16)
    int nchunk = 1;
    if (ws_size > used + perN) {
        size_t c = (ws_size - used) / perN;
        nchunk = (int)(c > NB ? NB : c);
    }

    hipLaunchKernelGGL(kA, dim3(DIM, NB), dim3(128), 0, stream, x, mask, w1, b1, ha, hb);
    hipLaunchKernelGGL(kW, dim3(OC * DIM / 256), dim3(256), 0, stream, w2, w2hi, w2lo);
    for (int base = 0; base < NB; base += nchunk) {
        int nc = nchunk < (NB - base) ? nchunk : (NB - base);
        hipLaunchKernelGGL(kB, dim3(LEN, nc), dim3(256), 0, stream, ha, hb, w2hi, w2lo, b2, y, base);
        hipLaunchKernelGGL(kC, dim3(OC * nc), dim3(1024), 65536, stream, y, pw, out, base);
    }
}